// Round 10
// baseline (355.620 us; speedup 1.0000x reference)
//
#include <hip/hip_runtime.h>
#include <hip/hip_bf16.h>

#define BB   8
#define SS   512
#define DD   128
#define HH   512
#define NBK  32

// ---- XCD-aware grids: gridDim.x = 8 = batch, so linear%8 == batch ----------

// ---------------- K1: embedding gather + positional --------------------------
__global__ void k_embed(const int* __restrict__ idx, const float* __restrict__ emb,
                        const float* __restrict__ pe, float* __restrict__ x) {
    int b = blockIdx.x;                            // batch
    int t = b * 16384 + blockIdx.y * 256 + threadIdx.x;  // float4 index
    int tok = t >> 5, d4 = (t & 31) * 4;
    float4 ev = *(const float4*)&emb[(size_t)idx[tok] * DD + d4];
    float4 pv = *(const float4*)&pe[b * DD + d4];
    ev.x += pv.x; ev.y += pv.y; ev.z += pv.z; ev.w += pv.w;
    *(float4*)&x[(size_t)tok * DD + d4] = ev;
}

// ------- K2: q,v = x@W+b + LSH bucket ids + qT (transposed q) ----------------
__global__ __launch_bounds__(256) void k_qvb(const float* __restrict__ x,
        const float* __restrict__ Wq, const float* __restrict__ bq,
        const float* __restrict__ Wv, const float* __restrict__ bv,
        const float* __restrict__ hyp,
        float* __restrict__ q, float* __restrict__ v, float* __restrict__ qT,
        int* __restrict__ bucket) {
    int rb = blockIdx.x * 32 + blockIdx.y;         // batch-major: XCD = batch
    __shared__ __align__(16) float xs[16][132];
    __shared__ float qts[128][17];                 // transposed q strip
    int tid = threadIdx.x;
    #pragma unroll
    for (int it = 0; it < 2; ++it) {
        int lin = tid + 256 * it;                  // 512 float4 slots
        int r = lin >> 5, kq = (lin & 31) * 4;
        *(float4*)&xs[r][kq] = *(const float4*)&x[(size_t)(rb * 16 + r) * DD + kq];
    }
    __syncthreads();
    int tx = tid & 63;                             // col pair (one wave per ty)
    int ty = tid >> 6;                             // row quad
    float2 aq[4], av[4];
    #pragma unroll
    for (int i = 0; i < 4; ++i) { aq[i] = make_float2(0.f, 0.f); av[i] = make_float2(0.f, 0.f); }
    for (int g = 0; g < 32; ++g) {
        int kb = g * 4;
        float4 a0 = *(const float4*)&xs[ty * 4 + 0][kb];
        float4 a1 = *(const float4*)&xs[ty * 4 + 1][kb];
        float4 a2 = *(const float4*)&xs[ty * 4 + 2][kb];
        float4 a3 = *(const float4*)&xs[ty * 4 + 3][kb];
        #pragma unroll
        for (int j = 0; j < 4; ++j) {
            float2 wq = *(const float2*)&Wq[(size_t)(kb + j) * DD + tx * 2];
            float2 wv = *(const float2*)&Wv[(size_t)(kb + j) * DD + tx * 2];
            float c0 = (j == 0) ? a0.x : (j == 1) ? a0.y : (j == 2) ? a0.z : a0.w;
            float c1 = (j == 0) ? a1.x : (j == 1) ? a1.y : (j == 2) ? a1.z : a1.w;
            float c2 = (j == 0) ? a2.x : (j == 1) ? a2.y : (j == 2) ? a2.z : a2.w;
            float c3 = (j == 0) ? a3.x : (j == 1) ? a3.y : (j == 2) ? a3.z : a3.w;
            aq[0].x += c0 * wq.x; aq[0].y += c0 * wq.y; av[0].x += c0 * wv.x; av[0].y += c0 * wv.y;
            aq[1].x += c1 * wq.x; aq[1].y += c1 * wq.y; av[1].x += c1 * wv.x; av[1].y += c1 * wv.y;
            aq[2].x += c2 * wq.x; aq[2].y += c2 * wq.y; av[2].x += c2 * wv.x; av[2].y += c2 * wv.y;
            aq[3].x += c3 * wq.x; aq[3].y += c3 * wq.y; av[3].x += c3 * wv.x; av[3].y += c3 * wv.y;
        }
    }
    float2 bqv = *(const float2*)&bq[tx * 2];
    float2 bvv = *(const float2*)&bv[tx * 2];
    float2 oq[4], ov[4];
    #pragma unroll
    for (int i = 0; i < 4; ++i) {
        oq[i] = make_float2(aq[i].x + bqv.x, aq[i].y + bqv.y);
        ov[i] = make_float2(av[i].x + bvv.x, av[i].y + bvv.y);
        int row = rb * 16 + ty * 4 + i;
        *(float2*)&q[(size_t)row * DD + tx * 2] = oq[i];
        *(float2*)&v[(size_t)row * DD + tx * 2] = ov[i];
        qts[2 * tx][ty * 4 + i]     = oq[i].x;     // LDS transpose
        qts[2 * tx + 1][ty * 4 + i] = oq[i].y;
    }
    // LSH projection: 5 hyperplanes; butterfly over the 64-lane wave
    float h0[5], h1[5];
    #pragma unroll
    for (int h = 0; h < 5; ++h) {
        h0[h] = hyp[(2 * tx) * 5 + h];
        h1[h] = hyp[(2 * tx + 1) * 5 + h];
    }
    float pr[4][5];
    #pragma unroll
    for (int r = 0; r < 4; ++r)
        #pragma unroll
        for (int h = 0; h < 5; ++h)
            pr[r][h] = oq[r].x * h0[h] + oq[r].y * h1[h];
    #pragma unroll
    for (int o = 1; o < 64; o <<= 1)
        #pragma unroll
        for (int r = 0; r < 4; ++r)
            #pragma unroll
            for (int h = 0; h < 5; ++h)
                pr[r][h] += __shfl_xor(pr[r][h], o, 64);
    if (tx == 0) {
        #pragma unroll
        for (int r = 0; r < 4; ++r) {
            int bb = 0;
            #pragma unroll
            for (int h = 0; h < 5; ++h)
                if (pr[r][h] + hyp[128 * 5 + h] >= 0.f) bb |= (1 << h);
            bucket[rb * 16 + ty * 4 + r] = bb;
        }
    }
    __syncthreads();
    // write qT[b][k][t]
    {
        int b  = blockIdx.x;
        int t0 = blockIdx.y * 16;
        int k  = tid >> 1, o = (tid & 1) * 8;
        float4 v0 = make_float4(qts[k][o], qts[k][o + 1], qts[k][o + 2], qts[k][o + 3]);
        float4 v1 = make_float4(qts[k][o + 4], qts[k][o + 5], qts[k][o + 6], qts[k][o + 7]);
        size_t base = ((size_t)b * DD + k) * SS + t0 + o;
        *(float4*)&qT[base]     = v0;
        *(float4*)&qT[base + 4] = v1;
    }
}

// ------- K3: Vb[b][bk][:] + cnt via masked scan, one block per (b,bk) --------
__global__ __launch_bounds__(256) void k_vb(const float* __restrict__ v,
        const int* __restrict__ bucket, float* __restrict__ Vb,
        int* __restrict__ cnt) {
    int b  = blockIdx.x;                           // 0..7  (XCD = batch)
    int bk = blockIdx.y;                           // 0..31
    int tid = threadIdx.x;
    __shared__ int bkt_sh[512];
    __shared__ float red[128];
    bkt_sh[tid]       = bucket[b * SS + tid];
    bkt_sh[tid + 256] = bucket[b * SS + tid + 256];
    __syncthreads();
    int d = tid & 127, half = tid >> 7;            // 2 halves x 256 tokens
    const float* vbp = v + (size_t)b * SS * DD + d;
    float acc = 0.f;
    #pragma unroll 8
    for (int i = 0; i < 256; ++i) {
        int tok = half * 256 + i;
        float val = vbp[(size_t)tok * DD];
        acc += (bkt_sh[tok] == bk) ? val : 0.f;
    }
    if (half == 1) red[d] = acc;
    __syncthreads();
    if (half == 0)
        Vb[(size_t)((b << 5) + bk) * DD + d] = acc + red[d];
    if (tid < 64) {
        int c = 0;
        #pragma unroll
        for (int i = 0; i < 8; ++i) c += (bkt_sh[tid * 8 + i] == bk) ? 1 : 0;
        #pragma unroll
        for (int o = 1; o < 64; o <<= 1) c += __shfl_xor(c, o, 64);
        if (tid == 0) cnt[(b << 5) + bk] = c;
    }
}

// ------ K5: fused QK^T + stats + C@V + uniform + LN.  8 rows, 512 thr --------
__global__ __launch_bounds__(512) void k_gattn(const float* __restrict__ qT,
        const float* __restrict__ q, const float* __restrict__ v,
        const int* __restrict__ bucket, const int* __restrict__ cnt,
        const float* __restrict__ Vb,
        const float* __restrict__ g, const float* __restrict__ lb,
        float* __restrict__ x) {
    int bz = blockIdx.x, s0 = blockIdx.y * 8;      // XCD = batch
    int tid = threadIdx.x;
    __shared__ __align__(16) float qs[8][132];     // q strip (A operand)
    __shared__ __align__(16) float cs[8][528];     // G strip -> e -> c
    __shared__ __align__(16) float osh[8][132];
    __shared__ int   bkt[512];
    __shared__ float Wsh[8][32];
    __shared__ float rsh[8][32];
    __shared__ float Zsh[8], Rsh[8], Msh[8];
    __shared__ float cntf[32];
    __shared__ int   bssh[8];
    {
        int r = tid >> 6, kq = (tid & 63) * 2;
        *(float2*)&qs[r][kq] = *(const float2*)&q[(size_t)(bz * SS + s0 + r) * DD + kq];
    }
    bkt[tid] = bucket[bz * SS + tid];
    if (tid < 32) cntf[tid] = (float)cnt[(bz << 5) + tid];
    if (tid < 8) bssh[tid] = bucket[bz * SS + s0 + tid];
    __syncthreads();
    const float scale = 0.088388347648318447f;
    // ---- Phase G: 4 col-chunks x (4 row-pairs x 32 colq), full k=128 ----
    {
        int cc  = tid >> 7;                        // col chunk 0..3
        int tyq = (tid >> 5) & 3;                  // row pair 0..3
        int txg = tid & 31;                        // col quad within 128
        float4 acc[2];
        acc[0] = make_float4(0.f, 0.f, 0.f, 0.f);
        acc[1] = make_float4(0.f, 0.f, 0.f, 0.f);
        const float* qtb = qT + (size_t)bz * DD * SS + cc * 128 + txg * 4;
        for (int gg = 0; gg < 32; ++gg) {
            int kb = gg * 4;
            float4 a0 = *(const float4*)&qs[tyq * 2 + 0][kb];
            float4 a1 = *(const float4*)&qs[tyq * 2 + 1][kb];
            #pragma unroll
            for (int j = 0; j < 4; ++j) {
                float4 b4 = *(const float4*)&qtb[(size_t)(kb + j) * SS];
                float c0 = (j == 0) ? a0.x : (j == 1) ? a0.y : (j == 2) ? a0.z : a0.w;
                float c1 = (j == 0) ? a1.x : (j == 1) ? a1.y : (j == 2) ? a1.z : a1.w;
                acc[0].x += c0 * b4.x; acc[0].y += c0 * b4.y; acc[0].z += c0 * b4.z; acc[0].w += c0 * b4.w;
                acc[1].x += c1 * b4.x; acc[1].y += c1 * b4.y; acc[1].z += c1 * b4.z; acc[1].w += c1 * b4.w;
            }
        }
        #pragma unroll
        for (int i = 0; i < 2; ++i) {
            float4 p;
            p.x = acc[i].x * scale; p.y = acc[i].y * scale;
            p.z = acc[i].z * scale; p.w = acc[i].w * scale;
            *(float4*)&cs[tyq * 2 + i][cc * 128 + txg * 4] = p;
        }
    }
    __syncthreads();
    // ---- row max (>=0) + Wsh init : 8 rows x 64 lanes ----
    int row = tid >> 6, l = tid & 63;
    {
        float m = 0.f;
        #pragma unroll
        for (int i = 0; i < 8; ++i) m = fmaxf(m, cs[row][l + 64 * i]);
        #pragma unroll
        for (int o = 1; o < 64; o <<= 1) m = fmaxf(m, __shfl_xor(m, o, 64));
        if (l == 0) Msh[row] = m;
        if (tid < 256) Wsh[tid >> 5][tid & 31] = 0.f;
    }
    __syncthreads();
    // ---- exp + per-bucket sums ----
    {
        float Ms = Msh[row];
        #pragma unroll
        for (int i = 0; i < 8; ++i) {
            int c = l + 64 * i;
            float ev = __expf(cs[row][c] - Ms);
            cs[row][c] = ev;
            atomicAdd(&Wsh[row][bkt[c]], ev);
        }
    }
    __syncthreads();
    if (tid < 8) {
        float z = 0.f;
        #pragma unroll
        for (int i = 0; i < NBK; ++i) z += Wsh[tid][i];
        Zsh[tid] = z;
    }
    __syncthreads();
    if (tid < 256) {
        int r = tid >> 5, bkid = tid & 31;
        rsh[r][bkid] = 1.0f / (Zsh[r] - Wsh[r][bkid] + cntf[bkid] * __expf(-Msh[r]));
    }
    __syncthreads();
    if (tid < 8) {
        int bs = bssh[tid];
        float R = 0.f;
        #pragma unroll
        for (int i = 0; i < NBK; ++i) R += (i == bs) ? 0.f : rsh[tid][i];
        Rsh[tid] = R;
    }
    __syncthreads();
    // ---- transform c = e * (R - r_{b_t}) ----
    {
        float R = Rsh[row];
        int bs = bssh[row];
        #pragma unroll
        for (int i = 0; i < 8; ++i) {
            int c = l + 64 * i;
            int bc = bkt[c];
            float rsel = (bc == bs) ? 0.f : rsh[row][bc];
            cs[row][c] *= (R - rsel);
        }
    }
    __syncthreads();
    // ---- C@V: 8 rows x 32 colq, split-K2; V from L2-local global ----
    {
        int kh = tid >> 8;                         // 0..1
        int ty = (tid >> 5) & 7;                   // row 0..7
        int tx = tid & 31;                         // col quad over D
        float4 acc = make_float4(0.f, 0.f, 0.f, 0.f);
        const float* vb_base = v + (size_t)bz * SS * DD + tx * 4;
        for (int gg = 0; gg < 64; ++gg) {
            int kb = kh * 256 + gg * 4;
            float4 a = *(const float4*)&cs[ty][kb];
            #pragma unroll
            for (int j = 0; j < 4; ++j) {
                float4 vj = *(const float4*)&vb_base[(size_t)(kb + j) * DD];
                float c = (j == 0) ? a.x : (j == 1) ? a.y : (j == 2) ? a.z : a.w;
                acc.x += c * vj.x; acc.y += c * vj.y; acc.z += c * vj.z; acc.w += c * vj.w;
            }
        }
        if (kh == 1)
            *(float4*)&osh[ty][tx * 4] = acc;
        __syncthreads();
        if (kh == 0) {
            float4 vs = make_float4(0.f, 0.f, 0.f, 0.f);
            #pragma unroll
            for (int i = 0; i < NBK; ++i) {
                float4 t = *(const float4*)&Vb[(size_t)((bz << 5) + i) * DD + tx * 4];
                vs.x += t.x; vs.y += t.y; vs.z += t.z; vs.w += t.w;
            }
            const float inv512 = 1.0f / 512.0f;
            int bs = bssh[ty];
            float4 vb4 = *(const float4*)&Vb[(size_t)((bz << 5) + bs) * DD + tx * 4];
            float4 p = *(const float4*)&osh[ty][tx * 4];
            p.x += acc.x + (vs.x - vb4.x) * inv512;
            p.y += acc.y + (vs.y - vb4.y) * inv512;
            p.z += acc.z + (vs.z - vb4.z) * inv512;
            p.w += acc.w + (vs.w - vb4.w) * inv512;
            *(float4*)&osh[ty][tx * 4] = p;
        }
    }
    __syncthreads();
    // ---- LayerNorm: 8 rows x 32 lanes, float4 each (first 256 threads) ----
    if (tid < 256) {
        int r = tid >> 5, ll = tid & 31;
        float4 val = *(const float4*)&osh[r][ll * 4];
        float s = val.x + val.y + val.z + val.w;
        float ss = val.x * val.x + val.y * val.y + val.z * val.z + val.w * val.w;
        #pragma unroll
        for (int o = 1; o < 32; o <<= 1) {
            s  += __shfl_xor(s, o, 32);
            ss += __shfl_xor(ss, o, 32);
        }
        float mean = s * (1.f / 128.f);
        float var = ss * (1.f / 128.f) - mean * mean;
        float rstd = rsqrtf(var + 1e-5f);
        float4 gv = *(const float4*)&g[ll * 4];
        float4 bv = *(const float4*)&lb[ll * 4];
        float4 out;
        out.x = (val.x - mean) * rstd * gv.x + bv.x;
        out.y = (val.y - mean) * rstd * gv.y + bv.y;
        out.z = (val.z - mean) * rstd * gv.z + bv.z;
        out.w = (val.w - mean) * rstd * gv.w + bv.w;
        *(float4*)&x[(size_t)(bz * SS + s0 + r) * DD + ll * 4] = out;
    }
}

// ------- K7: fused FFN: relu(x@W1+b1)@W2+b2 + x, LN -> x.  8 rows ------------
__global__ __launch_bounds__(512) void k_ffn(const float* __restrict__ x,
        const float* __restrict__ W1, const float* __restrict__ b1,
        const float* __restrict__ W2, const float* __restrict__ b2,
        const float* __restrict__ g, const float* __restrict__ lb,
        float* __restrict__ xout) {
    int rb = blockIdx.x * 64 + blockIdx.y;         // batch-major: XCD = batch
    int tid = threadIdx.x;
    __shared__ __align__(16) float xs[8][132];
    __shared__ __align__(16) float hs[8][520];
    __shared__ __align__(16) float osh[8][132];
    {
        int r = tid >> 6, kq = (tid & 63) * 2;
        *(float2*)&xs[r][kq] = *(const float2*)&x[(size_t)(rb * 8 + r) * DD + kq];
    }
    __syncthreads();
    // Phase B: h = relu(x@W1+b1), 4 row-pairs x 128 colq, full k=128
    {
        int typ = tid >> 7;                        // row pair 0..3
        int tx = tid & 127;                        // col quad of 512
        float4 acc[2];
        acc[0] = make_float4(0.f, 0.f, 0.f, 0.f);
        acc[1] = make_float4(0.f, 0.f, 0.f, 0.f);
        for (int gg = 0; gg < 32; ++gg) {
            int kb = gg * 4;
            float4 a0 = *(const float4*)&xs[typ * 2 + 0][kb];
            float4 a1 = *(const float4*)&xs[typ * 2 + 1][kb];
            #pragma unroll
            for (int j = 0; j < 4; ++j) {
                float4 w = *(const float4*)&W1[(size_t)(kb + j) * HH + tx * 4];
                float c0 = (j == 0) ? a0.x : (j == 1) ? a0.y : (j == 2) ? a0.z : a0.w;
                float c1 = (j == 0) ? a1.x : (j == 1) ? a1.y : (j == 2) ? a1.z : a1.w;
                acc[0].x += c0 * w.x; acc[0].y += c0 * w.y; acc[0].z += c0 * w.z; acc[0].w += c0 * w.w;
                acc[1].x += c1 * w.x; acc[1].y += c1 * w.y; acc[1].z += c1 * w.z; acc[1].w += c1 * w.w;
            }
        }
        float4 bi = *(const float4*)&b1[tx * 4];
        #pragma unroll
        for (int i = 0; i < 2; ++i) {
            float4 hv;
            hv.x = fmaxf(acc[i].x + bi.x, 0.f);
            hv.y = fmaxf(acc[i].y + bi.y, 0.f);
            hv.z = fmaxf(acc[i].z + bi.z, 0.f);
            hv.w = fmaxf(acc[i].w + bi.w, 0.f);
            *(float4*)&hs[typ * 2 + i][tx * 4] = hv;
        }
    }
    __syncthreads();
    // Phase C: y = h@W2, 8 rows x 32 colq, split-K2
    {
        int kh = tid >> 8;                         // 0..1
        int ty = (tid >> 5) & 7;                   // row 0..7
        int tx = tid & 31;
        float4 acc = make_float4(0.f, 0.f, 0.f, 0.f);
        for (int gg = 0; gg < 64; ++gg) {
            int kb = kh * 256 + gg * 4;
            float4 a = *(const float4*)&hs[ty][kb];
            #pragma unroll
            for (int j = 0; j < 4; ++j) {
                float4 w = *(const float4*)&W2[(size_t)(kb + j) * DD + tx * 4];
                float c = (j == 0) ? a.x : (j == 1) ? a.y : (j == 2) ? a.z : a.w;
                acc.x += c * w.x; acc.y += c * w.y; acc.z += c * w.z; acc.w += c * w.w;
            }
        }
        if (kh == 1)
            *(float4*)&osh[ty][tx * 4] = acc;
        __syncthreads();
        if (kh == 0) {
            float4 bi = *(const float4*)&b2[tx * 4];
            float4 res = *(const float4*)&xs[ty][tx * 4];
            float4 p = *(const float4*)&osh[ty][tx * 4];
            p.x += acc.x + bi.x + res.x;
            p.y += acc.y + bi.y + res.y;
            p.z += acc.z + bi.z + res.z;
            p.w += acc.w + bi.w + res.w;
            *(float4*)&osh[ty][tx * 4] = p;
        }
    }
    __syncthreads();
    // LayerNorm: 8 rows x 32 lanes (first 256 threads)
    if (tid < 256) {
        int row = tid >> 5, l = tid & 31;
        float4 val = *(const float4*)&osh[row][l * 4];
        float s = val.x + val.y + val.z + val.w;
        float ss = val.x * val.x + val.y * val.y + val.z * val.z + val.w * val.w;
        #pragma unroll
        for (int o = 1; o < 32; o <<= 1) {
            s  += __shfl_xor(s, o, 32);
            ss += __shfl_xor(ss, o, 32);
        }
        float mean = s * (1.f / 128.f);
        float var = ss * (1.f / 128.f) - mean * mean;
        float rstd = rsqrtf(var + 1e-5f);
        float4 gv = *(const float4*)&g[l * 4];
        float4 bv = *(const float4*)&lb[l * 4];
        float4 out;
        out.x = (val.x - mean) * rstd * gv.x + bv.x;
        out.y = (val.y - mean) * rstd * gv.y + bv.y;
        out.z = (val.z - mean) * rstd * gv.z + bv.z;
        out.w = (val.w - mean) * rstd * gv.w + bv.w;
        *(float4*)&xout[(size_t)(rb * 8 + row) * DD + l * 4] = out;
    }
}

// ---------------- K9: out = x_flat @ Wm + bm (split-K + atomics) -------------
__global__ __launch_bounds__(256) void k_final(const float* __restrict__ x,
        const float* __restrict__ Wm, const float* __restrict__ bm,
        float* __restrict__ out) {
    int b = blockIdx.x >> 5, chunk = blockIdx.x & 31;   // 2048 elems per chunk
    int tid = threadIdx.x;
    const float* xr = x + (size_t)b * 65536 + chunk * 2048;
    const float* wr = Wm + (size_t)(chunk * 2048) * 6;
    float p[6] = {0.f, 0.f, 0.f, 0.f, 0.f, 0.f};
    #pragma unroll
    for (int it = 0; it < 8; ++it) {
        int j = tid + 256 * it;
        float xv = xr[j];
        const float* w = wr + (size_t)j * 6;
        p[0] += xv * w[0]; p[1] += xv * w[1]; p[2] += xv * w[2];
        p[3] += xv * w[3]; p[4] += xv * w[4]; p[5] += xv * w[5];
    }
    #pragma unroll
    for (int o = 0; o < 6; ++o)
        #pragma unroll
        for (int off = 1; off < 64; off <<= 1)
            p[o] += __shfl_xor(p[o], off, 64);
    __shared__ float red[4][6];
    int wv = tid >> 6;
    if ((tid & 63) == 0)
        #pragma unroll
        for (int o = 0; o < 6; ++o) red[wv][o] = p[o];
    __syncthreads();
    if (tid < 6) {
        float sv = red[0][tid] + red[1][tid] + red[2][tid] + red[3][tid];
        if (chunk == 0) sv += bm[tid];
        atomicAdd(&out[b * 6 + tid], sv);
    }
}

// ---------------- orchestration ----------------------------------------------
extern "C" void kernel_launch(void* const* d_in, const int* in_sizes, int n_in,
                              void* d_out, int out_size, void* d_ws, size_t ws_size,
                              hipStream_t stream) {
    const int*   inputs = (const int*)  d_in[0];
    const float* emb    = (const float*)d_in[1];
    const float* pe     = (const float*)d_in[2];
    const float* hyp    = (const float*)d_in[3];
    const float* Wq     = (const float*)d_in[4];
    const float* bq     = (const float*)d_in[5];
    const float* Wv     = (const float*)d_in[6];
    const float* bv     = (const float*)d_in[7];
    const float* ln_g   = (const float*)d_in[8];
    const float* ln_b   = (const float*)d_in[9];
    const float* W1     = (const float*)d_in[10];
    const float* b1     = (const float*)d_in[11];
    const float* W2     = (const float*)d_in[12];
    const float* b2     = (const float*)d_in[13];
    const float* Wm     = (const float*)d_in[14];
    const float* bm     = (const float*)d_in[15];

    float* F = (float*)d_ws;
    float* x     = F + 0;          // 524288
    float* q     = F + 524288;     // 524288
    float* v     = F + 1048576;    // 524288
    float* qT    = F + 1572864;    // 524288  [b][k][t]
    float* Vb    = F + 2097152;    // 32768   (plain stores)
    int*   cnt   = (int*)(F + 2129920);  // 256 ints
    int*   bucket= (int*)(F + 2130176);  // 4096 ints

    hipMemsetAsync(d_out, 0, (size_t)out_size * 4, stream);
    k_embed<<<dim3(8, 64), 256, 0, stream>>>(inputs, emb, pe, x);

    for (int enc = 0; enc < 2; ++enc) {
        k_qvb<<<dim3(8, 32), 256, 0, stream>>>(x, Wq, bq, Wv, bv, hyp, q, v, qT, bucket);
        k_vb<<<dim3(8, 32), 256, 0, stream>>>(v, bucket, Vb, cnt);
        k_gattn<<<dim3(8, 64), 512, 0, stream>>>(qT, q, v, bucket, cnt, Vb, ln_g, ln_b, x);
        k_ffn<<<dim3(8, 64), 512, 0, stream>>>(x, W1, b1, W2, b2, ln_g, ln_b, x);
    }
    k_final<<<48 * 32 / 6, 256, 0, stream>>>(x, Wm, bm, (float*)d_out);
}

// Round 11
// 249.041 us; speedup vs baseline: 1.4280x; 1.4280x over previous
//
#include <hip/hip_runtime.h>
#include <hip/hip_bf16.h>

#define BB   8
#define SS   512
#define DD   128
#define HH   512
#define NBK  32

// ---- XCD-aware grids: gridDim.x = 8 = batch, so linear%8 == batch ----------

// ---------------- K1: embedding gather + positional --------------------------
__global__ void k_embed(const int* __restrict__ idx, const float* __restrict__ emb,
                        const float* __restrict__ pe, float* __restrict__ x) {
    int b = blockIdx.x;                            // batch
    int t = b * 16384 + blockIdx.y * 256 + threadIdx.x;  // float4 index
    int tok = t >> 5, d4 = (t & 31) * 4;
    float4 ev = *(const float4*)&emb[(size_t)idx[tok] * DD + d4];
    float4 pv = *(const float4*)&pe[b * DD + d4];
    ev.x += pv.x; ev.y += pv.y; ev.z += pv.z; ev.w += pv.w;
    *(float4*)&x[(size_t)tok * DD + d4] = ev;
}

// ------- K2: q,v = x@W+b + LSH bucket ids + qT (transposed q) ----------------
__global__ __launch_bounds__(256) void k_qvb(const float* __restrict__ x,
        const float* __restrict__ Wq, const float* __restrict__ bq,
        const float* __restrict__ Wv, const float* __restrict__ bv,
        const float* __restrict__ hyp,
        float* __restrict__ q, float* __restrict__ v, float* __restrict__ qT,
        int* __restrict__ bucket) {
    int rb = blockIdx.x * 32 + blockIdx.y;         // batch-major: XCD = batch
    __shared__ __align__(16) float xs[16][132];
    __shared__ float qts[128][17];                 // transposed q strip
    int tid = threadIdx.x;
    #pragma unroll
    for (int it = 0; it < 2; ++it) {
        int lin = tid + 256 * it;                  // 512 float4 slots
        int r = lin >> 5, kq = (lin & 31) * 4;
        *(float4*)&xs[r][kq] = *(const float4*)&x[(size_t)(rb * 16 + r) * DD + kq];
    }
    __syncthreads();
    int tx = tid & 63;                             // col pair (one wave per ty)
    int ty = tid >> 6;                             // row quad
    float2 aq[4], av[4];
    #pragma unroll
    for (int i = 0; i < 4; ++i) { aq[i] = make_float2(0.f, 0.f); av[i] = make_float2(0.f, 0.f); }
    for (int g = 0; g < 32; ++g) {
        int kb = g * 4;
        float4 a0 = *(const float4*)&xs[ty * 4 + 0][kb];
        float4 a1 = *(const float4*)&xs[ty * 4 + 1][kb];
        float4 a2 = *(const float4*)&xs[ty * 4 + 2][kb];
        float4 a3 = *(const float4*)&xs[ty * 4 + 3][kb];
        #pragma unroll
        for (int j = 0; j < 4; ++j) {
            float2 wq = *(const float2*)&Wq[(size_t)(kb + j) * DD + tx * 2];
            float2 wv = *(const float2*)&Wv[(size_t)(kb + j) * DD + tx * 2];
            float c0 = (j == 0) ? a0.x : (j == 1) ? a0.y : (j == 2) ? a0.z : a0.w;
            float c1 = (j == 0) ? a1.x : (j == 1) ? a1.y : (j == 2) ? a1.z : a1.w;
            float c2 = (j == 0) ? a2.x : (j == 1) ? a2.y : (j == 2) ? a2.z : a2.w;
            float c3 = (j == 0) ? a3.x : (j == 1) ? a3.y : (j == 2) ? a3.z : a3.w;
            aq[0].x += c0 * wq.x; aq[0].y += c0 * wq.y; av[0].x += c0 * wv.x; av[0].y += c0 * wv.y;
            aq[1].x += c1 * wq.x; aq[1].y += c1 * wq.y; av[1].x += c1 * wv.x; av[1].y += c1 * wv.y;
            aq[2].x += c2 * wq.x; aq[2].y += c2 * wq.y; av[2].x += c2 * wv.x; av[2].y += c2 * wv.y;
            aq[3].x += c3 * wq.x; aq[3].y += c3 * wq.y; av[3].x += c3 * wv.x; av[3].y += c3 * wv.y;
        }
    }
    float2 bqv = *(const float2*)&bq[tx * 2];
    float2 bvv = *(const float2*)&bv[tx * 2];
    float2 oq[4], ov[4];
    #pragma unroll
    for (int i = 0; i < 4; ++i) {
        oq[i] = make_float2(aq[i].x + bqv.x, aq[i].y + bqv.y);
        ov[i] = make_float2(av[i].x + bvv.x, av[i].y + bvv.y);
        int row = rb * 16 + ty * 4 + i;
        *(float2*)&q[(size_t)row * DD + tx * 2] = oq[i];
        *(float2*)&v[(size_t)row * DD + tx * 2] = ov[i];
        qts[2 * tx][ty * 4 + i]     = oq[i].x;     // LDS transpose
        qts[2 * tx + 1][ty * 4 + i] = oq[i].y;
    }
    // LSH projection: 5 hyperplanes; butterfly over the 64-lane wave
    float h0[5], h1[5];
    #pragma unroll
    for (int h = 0; h < 5; ++h) {
        h0[h] = hyp[(2 * tx) * 5 + h];
        h1[h] = hyp[(2 * tx + 1) * 5 + h];
    }
    float pr[4][5];
    #pragma unroll
    for (int r = 0; r < 4; ++r)
        #pragma unroll
        for (int h = 0; h < 5; ++h)
            pr[r][h] = oq[r].x * h0[h] + oq[r].y * h1[h];
    #pragma unroll
    for (int o = 1; o < 64; o <<= 1)
        #pragma unroll
        for (int r = 0; r < 4; ++r)
            #pragma unroll
            for (int h = 0; h < 5; ++h)
                pr[r][h] += __shfl_xor(pr[r][h], o, 64);
    if (tx == 0) {
        #pragma unroll
        for (int r = 0; r < 4; ++r) {
            int bb = 0;
            #pragma unroll
            for (int h = 0; h < 5; ++h)
                if (pr[r][h] + hyp[128 * 5 + h] >= 0.f) bb |= (1 << h);
            bucket[rb * 16 + ty * 4 + r] = bb;
        }
    }
    __syncthreads();
    // write qT[b][k][t]
    {
        int b  = blockIdx.x;
        int t0 = blockIdx.y * 16;
        int k  = tid >> 1, o = (tid & 1) * 8;
        float4 v0 = make_float4(qts[k][o], qts[k][o + 1], qts[k][o + 2], qts[k][o + 3]);
        float4 v1 = make_float4(qts[k][o + 4], qts[k][o + 5], qts[k][o + 6], qts[k][o + 7]);
        size_t base = ((size_t)b * DD + k) * SS + t0 + o;
        *(float4*)&qT[base]     = v0;
        *(float4*)&qT[base + 4] = v1;
    }
}

// ------- K3: Vb[b][bk][:] + cnt via masked scan, one block per (b,bk) --------
__global__ __launch_bounds__(256) void k_vb(const float* __restrict__ v,
        const int* __restrict__ bucket, float* __restrict__ Vb,
        int* __restrict__ cnt) {
    int b  = blockIdx.x;                           // 0..7  (XCD = batch)
    int bk = blockIdx.y;                           // 0..31
    int tid = threadIdx.x;
    __shared__ int bkt_sh[512];
    __shared__ float red[128];
    bkt_sh[tid]       = bucket[b * SS + tid];
    bkt_sh[tid + 256] = bucket[b * SS + tid + 256];
    __syncthreads();
    int d = tid & 127, half = tid >> 7;            // 2 halves x 256 tokens
    const float* vbp = v + (size_t)b * SS * DD + d;
    float acc = 0.f;
    #pragma unroll 8
    for (int i = 0; i < 256; ++i) {
        int tok = half * 256 + i;
        float val = vbp[(size_t)tok * DD];
        acc += (bkt_sh[tok] == bk) ? val : 0.f;
    }
    if (half == 1) red[d] = acc;
    __syncthreads();
    if (half == 0)
        Vb[(size_t)((b << 5) + bk) * DD + d] = acc + red[d];
    if (tid < 64) {
        int c = 0;
        #pragma unroll
        for (int i = 0; i < 8; ++i) c += (bkt_sh[tid * 8 + i] == bk) ? 1 : 0;
        #pragma unroll
        for (int o = 1; o < 64; o <<= 1) c += __shfl_xor(c, o, 64);
        if (tid == 0) cnt[(b << 5) + bk] = c;
    }
}

// ------ K5: fused QK^T + stats + C@V + uniform + LN. 16 rows, 8-row micro ----
__global__ __launch_bounds__(512) void k_gattn(const float* __restrict__ qT,
        const float* __restrict__ q, const float* __restrict__ v,
        const int* __restrict__ bucket, const int* __restrict__ cnt,
        const float* __restrict__ Vb,
        const float* __restrict__ g, const float* __restrict__ lb,
        float* __restrict__ x) {
    int bz = blockIdx.x, s0 = blockIdx.y * 16;     // XCD = batch
    int tid = threadIdx.x;
    __shared__ __align__(16) float qs[16][132];    // q strip (A operand)
    __shared__ __align__(16) float cs[16][528];    // G strip -> e -> c
    __shared__ __align__(16) float osh[16][132];
    __shared__ int   bkt[512];
    __shared__ float Wsh[16][32];
    __shared__ float rsh[16][32];
    __shared__ float Zsh[16], Rsh[16], Msh[16];
    __shared__ float cntf[32];
    __shared__ int   bssh[16];
    {
        int r = tid >> 5, kq = (tid & 31) * 4;
        *(float4*)&qs[r][kq] = *(const float4*)&q[(size_t)(bz * SS + s0 + r) * DD + kq];
    }
    bkt[tid] = bucket[bz * SS + tid];
    if (tid < 32) cntf[tid] = (float)cnt[(bz << 5) + tid];
    if (tid < 16) bssh[tid] = bucket[bz * SS + s0 + tid];
    Wsh[tid >> 5][tid & 31] = 0.f;
    __syncthreads();
    const float scale = 0.088388347648318447f;
    // ---- Phase G: split-K2 x 2 row-octets x 128 col-quads, 8-row micro ----
    {
        int kh   = tid >> 8;                       // 0..1 : k half (64)
        int rg   = (tid >> 7) & 1;                 // row octet 0..1
        int slot = tid & 127;                      // col quad (512 cols)
        float4 acc[8];
        #pragma unroll
        for (int i = 0; i < 8; ++i) acc[i] = make_float4(0.f, 0.f, 0.f, 0.f);
        const float* qtb = qT + (size_t)bz * DD * SS + (size_t)kh * 64 * SS + slot * 4;
        for (int gg = 0; gg < 16; ++gg) {
            int kb = kh * 64 + gg * 4;
            float4 a[8];
            #pragma unroll
            for (int i = 0; i < 8; ++i) a[i] = *(const float4*)&qs[rg * 8 + i][kb];
            #pragma unroll
            for (int j = 0; j < 4; ++j) {
                float4 b4 = *(const float4*)&qtb[(size_t)(gg * 4 + j) * SS];
                #pragma unroll
                for (int i = 0; i < 8; ++i) {
                    float c = (j == 0) ? a[i].x : (j == 1) ? a[i].y : (j == 2) ? a[i].z : a[i].w;
                    acc[i].x += c * b4.x; acc[i].y += c * b4.y;
                    acc[i].z += c * b4.z; acc[i].w += c * b4.w;
                }
            }
        }
        if (kh == 1) {
            #pragma unroll
            for (int i = 0; i < 8; ++i)
                *(float4*)&cs[rg * 8 + i][slot * 4] = acc[i];
        }
        __syncthreads();
        if (kh == 0) {
            #pragma unroll
            for (int i = 0; i < 8; ++i) {
                float4 p = *(const float4*)&cs[rg * 8 + i][slot * 4];
                p.x = (p.x + acc[i].x) * scale;
                p.y = (p.y + acc[i].y) * scale;
                p.z = (p.z + acc[i].z) * scale;
                p.w = (p.w + acc[i].w) * scale;
                *(float4*)&cs[rg * 8 + i][slot * 4] = p;
            }
        }
        __syncthreads();
    }
    // ---- row max (>=0) : 16 rows x 32 lanes ----
    int row = tid >> 5, l = tid & 31;
    {
        float m = 0.f;
        #pragma unroll
        for (int i = 0; i < 16; ++i) m = fmaxf(m, cs[row][l + 32 * i]);
        #pragma unroll
        for (int o = 1; o < 32; o <<= 1) m = fmaxf(m, __shfl_xor(m, o, 32));
        if (l == 0) Msh[row] = m;
    }
    __syncthreads();
    // ---- exp + per-bucket sums ----
    {
        float Ms = Msh[row];
        #pragma unroll
        for (int i = 0; i < 16; ++i) {
            int c = l + 32 * i;
            float ev = __expf(cs[row][c] - Ms);
            cs[row][c] = ev;
            atomicAdd(&Wsh[row][bkt[c]], ev);
        }
    }
    __syncthreads();
    if (tid < 16) {
        float z = 0.f;
        #pragma unroll
        for (int i = 0; i < NBK; ++i) z += Wsh[tid][i];
        Zsh[tid] = z;
    }
    __syncthreads();
    rsh[row][l] = 1.0f / (Zsh[row] - Wsh[row][l] + cntf[l] * __expf(-Msh[row]));
    __syncthreads();
    if (tid < 16) {
        int bs = bssh[tid];
        float R = 0.f;
        #pragma unroll
        for (int i = 0; i < NBK; ++i) R += (i == bs) ? 0.f : rsh[tid][i];
        Rsh[tid] = R;
    }
    __syncthreads();
    // ---- transform c = e * (R - r_{b_t}) ----
    {
        float R = Rsh[row];
        int bs = bssh[row];
        #pragma unroll
        for (int i = 0; i < 16; ++i) {
            int c = l + 32 * i;
            int bc = bkt[c];
            float rsel = (bc == bs) ? 0.f : rsh[row][bc];
            cs[row][c] *= (R - rsel);
        }
    }
    __syncthreads();
    // ---- C@V: split-K4 x 2 row-octets x 64 col-pairs (8-row micro) ----
    {
        int kh = tid >> 7;                         // 0..3 : k chunk of 128
        int rg = (tid >> 6) & 1;                   // row octet
        int cp = tid & 63;                         // col pair over D
        float2 acc[8];
        #pragma unroll
        for (int i = 0; i < 8; ++i) acc[i] = make_float2(0.f, 0.f);
        const float* vb_base = v + (size_t)bz * SS * DD + cp * 2;
        for (int gg = 0; gg < 32; ++gg) {
            int kb = kh * 128 + gg * 4;
            float4 a[8];
            #pragma unroll
            for (int i = 0; i < 8; ++i) a[i] = *(const float4*)&cs[rg * 8 + i][kb];
            #pragma unroll
            for (int j = 0; j < 4; ++j) {
                float2 v2 = *(const float2*)&vb_base[(size_t)(kb + j) * DD];
                #pragma unroll
                for (int i = 0; i < 8; ++i) {
                    float c = (j == 0) ? a[i].x : (j == 1) ? a[i].y : (j == 2) ? a[i].z : a[i].w;
                    acc[i].x += c * v2.x; acc[i].y += c * v2.y;
                }
            }
        }
        if (kh == 3) {
            #pragma unroll
            for (int i = 0; i < 8; ++i)
                *(float2*)&osh[rg * 8 + i][cp * 2] = acc[i];
        }
        __syncthreads();
        #pragma unroll
        for (int p = 2; p >= 1; --p) {
            if (kh == p) {
                #pragma unroll
                for (int i = 0; i < 8; ++i) {
                    float2 o = *(const float2*)&osh[rg * 8 + i][cp * 2];
                    o.x += acc[i].x; o.y += acc[i].y;
                    *(float2*)&osh[rg * 8 + i][cp * 2] = o;
                }
            }
            __syncthreads();
        }
        if (kh == 0) {
            float2 vs = make_float2(0.f, 0.f);
            #pragma unroll
            for (int i = 0; i < NBK; ++i) {
                float2 t = *(const float2*)&Vb[(size_t)((bz << 5) + i) * DD + cp * 2];
                vs.x += t.x; vs.y += t.y;
            }
            const float inv512 = 1.0f / 512.0f;
            #pragma unroll
            for (int i = 0; i < 8; ++i) {
                int r = rg * 8 + i;
                int bs = bssh[r];
                float2 vb2 = *(const float2*)&Vb[(size_t)((bz << 5) + bs) * DD + cp * 2];
                float2 p = *(const float2*)&osh[r][cp * 2];
                p.x += acc[i].x + (vs.x - vb2.x) * inv512;
                p.y += acc[i].y + (vs.y - vb2.y) * inv512;
                *(float2*)&osh[r][cp * 2] = p;
            }
        }
        __syncthreads();
    }
    // ---- LayerNorm: 16 rows x 32 lanes, float4 each ----
    {
        float4 val = *(const float4*)&osh[row][l * 4];
        float s = val.x + val.y + val.z + val.w;
        float ss = val.x * val.x + val.y * val.y + val.z * val.z + val.w * val.w;
        #pragma unroll
        for (int o = 1; o < 32; o <<= 1) {
            s  += __shfl_xor(s, o, 32);
            ss += __shfl_xor(ss, o, 32);
        }
        float mean = s * (1.f / 128.f);
        float var = ss * (1.f / 128.f) - mean * mean;
        float rstd = rsqrtf(var + 1e-5f);
        float4 gv = *(const float4*)&g[l * 4];
        float4 bv = *(const float4*)&lb[l * 4];
        float4 out;
        out.x = (val.x - mean) * rstd * gv.x + bv.x;
        out.y = (val.y - mean) * rstd * gv.y + bv.y;
        out.z = (val.z - mean) * rstd * gv.z + bv.z;
        out.w = (val.w - mean) * rstd * gv.w + bv.w;
        *(float4*)&x[(size_t)(bz * SS + s0 + row) * DD + l * 4] = out;
    }
}

// ------- K7: fused FFN, 16 rows, 8-row micro, split-K merges -----------------
__global__ __launch_bounds__(512) void k_ffn(const float* __restrict__ x,
        const float* __restrict__ W1, const float* __restrict__ b1,
        const float* __restrict__ W2, const float* __restrict__ b2,
        const float* __restrict__ g, const float* __restrict__ lb,
        float* __restrict__ xout) {
    int rb = blockIdx.x * 32 + blockIdx.y;         // batch-major: XCD = batch
    int tid = threadIdx.x;
    __shared__ __align__(16) float xs[16][132];
    __shared__ __align__(16) float hs[16][520];
    __shared__ __align__(16) float osh[16][132];
    {
        int r = tid >> 5, kq = (tid & 31) * 4;
        *(float4*)&xs[r][kq] = *(const float4*)&x[(size_t)(rb * 16 + r) * DD + kq];
    }
    __syncthreads();
    // Phase B: h = relu(x@W1+b1): split-K2 x 2 row-octets x 128 col-quads
    {
        int kh   = tid >> 8;                       // 0..1 : k half (64)
        int rg   = (tid >> 7) & 1;                 // row octet
        int slot = tid & 127;                      // col quad (512 cols)
        float4 acc[8];
        #pragma unroll
        for (int i = 0; i < 8; ++i) acc[i] = make_float4(0.f, 0.f, 0.f, 0.f);
        for (int gg = 0; gg < 16; ++gg) {
            int kb = kh * 64 + gg * 4;
            float4 a[8];
            #pragma unroll
            for (int i = 0; i < 8; ++i) a[i] = *(const float4*)&xs[rg * 8 + i][kb];
            #pragma unroll
            for (int j = 0; j < 4; ++j) {
                float4 w = *(const float4*)&W1[(size_t)(kb + j) * HH + slot * 4];
                #pragma unroll
                for (int i = 0; i < 8; ++i) {
                    float c = (j == 0) ? a[i].x : (j == 1) ? a[i].y : (j == 2) ? a[i].z : a[i].w;
                    acc[i].x += c * w.x; acc[i].y += c * w.y;
                    acc[i].z += c * w.z; acc[i].w += c * w.w;
                }
            }
        }
        if (kh == 1) {
            #pragma unroll
            for (int i = 0; i < 8; ++i)
                *(float4*)&hs[rg * 8 + i][slot * 4] = acc[i];
        }
        __syncthreads();
        if (kh == 0) {
            float4 bi = *(const float4*)&b1[slot * 4];
            #pragma unroll
            for (int i = 0; i < 8; ++i) {
                float4 p = *(const float4*)&hs[rg * 8 + i][slot * 4];
                p.x = fmaxf(p.x + acc[i].x + bi.x, 0.f);
                p.y = fmaxf(p.y + acc[i].y + bi.y, 0.f);
                p.z = fmaxf(p.z + acc[i].z + bi.z, 0.f);
                p.w = fmaxf(p.w + acc[i].w + bi.w, 0.f);
                *(float4*)&hs[rg * 8 + i][slot * 4] = p;
            }
        }
        __syncthreads();
    }
    // Phase C: y = h@W2: split-K4 x 2 row-octets x 64 col-pairs
    {
        int kh = tid >> 7;                         // 0..3 : k chunk of 128
        int rg = (tid >> 6) & 1;                   // row octet
        int cp = tid & 63;                         // col pair over D
        float2 acc[8];
        #pragma unroll
        for (int i = 0; i < 8; ++i) acc[i] = make_float2(0.f, 0.f);
        for (int gg = 0; gg < 32; ++gg) {
            int kb = kh * 128 + gg * 4;
            float4 a[8];
            #pragma unroll
            for (int i = 0; i < 8; ++i) a[i] = *(const float4*)&hs[rg * 8 + i][kb];
            #pragma unroll
            for (int j = 0; j < 4; ++j) {
                float2 w2 = *(const float2*)&W2[(size_t)(kb + j) * DD + cp * 2];
                #pragma unroll
                for (int i = 0; i < 8; ++i) {
                    float c = (j == 0) ? a[i].x : (j == 1) ? a[i].y : (j == 2) ? a[i].z : a[i].w;
                    acc[i].x += c * w2.x; acc[i].y += c * w2.y;
                }
            }
        }
        if (kh == 3) {
            #pragma unroll
            for (int i = 0; i < 8; ++i)
                *(float2*)&osh[rg * 8 + i][cp * 2] = acc[i];
        }
        __syncthreads();
        #pragma unroll
        for (int p = 2; p >= 1; --p) {
            if (kh == p) {
                #pragma unroll
                for (int i = 0; i < 8; ++i) {
                    float2 o = *(const float2*)&osh[rg * 8 + i][cp * 2];
                    o.x += acc[i].x; o.y += acc[i].y;
                    *(float2*)&osh[rg * 8 + i][cp * 2] = o;
                }
            }
            __syncthreads();
        }
        if (kh == 0) {
            float2 bi = *(const float2*)&b2[cp * 2];
            #pragma unroll
            for (int i = 0; i < 8; ++i) {
                int r = rg * 8 + i;
                float2 res = *(const float2*)&xs[r][cp * 2];
                float2 p = *(const float2*)&osh[r][cp * 2];
                p.x += acc[i].x + bi.x + res.x;
                p.y += acc[i].y + bi.y + res.y;
                *(float2*)&osh[r][cp * 2] = p;
            }
        }
        __syncthreads();
    }
    // LayerNorm: 16 rows x 32 lanes, float4 each
    int row = tid >> 5, l = tid & 31;
    float4 val = *(const float4*)&osh[row][l * 4];
    float s = val.x + val.y + val.z + val.w;
    float ss = val.x * val.x + val.y * val.y + val.z * val.z + val.w * val.w;
    #pragma unroll
    for (int o = 1; o < 32; o <<= 1) {
        s  += __shfl_xor(s, o, 32);
        ss += __shfl_xor(ss, o, 32);
    }
    float mean = s * (1.f / 128.f);
    float var = ss * (1.f / 128.f) - mean * mean;
    float rstd = rsqrtf(var + 1e-5f);
    float4 gv = *(const float4*)&g[l * 4];
    float4 bv = *(const float4*)&lb[l * 4];
    float4 out;
    out.x = (val.x - mean) * rstd * gv.x + bv.x;
    out.y = (val.y - mean) * rstd * gv.y + bv.y;
    out.z = (val.z - mean) * rstd * gv.z + bv.z;
    out.w = (val.w - mean) * rstd * gv.w + bv.w;
    *(float4*)&xout[(size_t)(rb * 16 + row) * DD + l * 4] = out;
}

// ---------------- K9: out = x_flat @ Wm + bm (split-K + atomics) -------------
__global__ __launch_bounds__(256) void k_final(const float* __restrict__ x,
        const float* __restrict__ Wm, const float* __restrict__ bm,
        float* __restrict__ out) {
    int b = blockIdx.x >> 5, chunk = blockIdx.x & 31;   // 2048 elems per chunk
    int tid = threadIdx.x;
    const float* xr = x + (size_t)b * 65536 + chunk * 2048;
    const float* wr = Wm + (size_t)(chunk * 2048) * 6;
    float p[6] = {0.f, 0.f, 0.f, 0.f, 0.f, 0.f};
    #pragma unroll
    for (int it = 0; it < 8; ++it) {
        int j = tid + 256 * it;
        float xv = xr[j];
        const float* w = wr + (size_t)j * 6;
        p[0] += xv * w[0]; p[1] += xv * w[1]; p[2] += xv * w[2];
        p[3] += xv * w[3]; p[4] += xv * w[4]; p[5] += xv * w[5];
    }
    #pragma unroll
    for (int o = 0; o < 6; ++o)
        #pragma unroll
        for (int off = 1; off < 64; off <<= 1)
            p[o] += __shfl_xor(p[o], off, 64);
    __shared__ float red[4][6];
    int wv = tid >> 6;
    if ((tid & 63) == 0)
        #pragma unroll
        for (int o = 0; o < 6; ++o) red[wv][o] = p[o];
    __syncthreads();
    if (tid < 6) {
        float sv = red[0][tid] + red[1][tid] + red[2][tid] + red[3][tid];
        if (chunk == 0) sv += bm[tid];
        atomicAdd(&out[b * 6 + tid], sv);
    }
}

// ---------------- orchestration ----------------------------------------------
extern "C" void kernel_launch(void* const* d_in, const int* in_sizes, int n_in,
                              void* d_out, int out_size, void* d_ws, size_t ws_size,
                              hipStream_t stream) {
    const int*   inputs = (const int*)  d_in[0];
    const float* emb    = (const float*)d_in[1];
    const float* pe     = (const float*)d_in[2];
    const float* hyp    = (const float*)d_in[3];
    const float* Wq     = (const float*)d_in[4];
    const float* bq     = (const float*)d_in[5];
    const float* Wv     = (const float*)d_in[6];
    const float* bv     = (const float*)d_in[7];
    const float* ln_g   = (const float*)d_in[8];
    const float* ln_b   = (const float*)d_in[9];
    const float* W1     = (const float*)d_in[10];
    const float* b1     = (const float*)d_in[11];
    const float* W2     = (const float*)d_in[12];
    const float* b2     = (const float*)d_in[13];
    const float* Wm     = (const float*)d_in[14];
    const float* bm     = (const float*)d_in[15];

    float* F = (float*)d_ws;
    float* x     = F + 0;          // 524288
    float* q     = F + 524288;     // 524288
    float* v     = F + 1048576;    // 524288
    float* qT    = F + 1572864;    // 524288  [b][k][t]
    float* Vb    = F + 2097152;    // 32768   (plain stores)
    int*   cnt   = (int*)(F + 2129920);  // 256 ints
    int*   bucket= (int*)(F + 2130176);  // 4096 ints

    hipMemsetAsync(d_out, 0, (size_t)out_size * 4, stream);
    k_embed<<<dim3(8, 64), 256, 0, stream>>>(inputs, emb, pe, x);

    for (int enc = 0; enc < 2; ++enc) {
        k_qvb<<<dim3(8, 32), 256, 0, stream>>>(x, Wq, bq, Wv, bv, hyp, q, v, qT, bucket);
        k_vb<<<dim3(8, 32), 256, 0, stream>>>(v, bucket, Vb, cnt);
        k_gattn<<<dim3(8, 32), 512, 0, stream>>>(qT, q, v, bucket, cnt, Vb, ln_g, ln_b, x);
        k_ffn<<<dim3(8, 32), 512, 0, stream>>>(x, W1, b1, W2, b2, ln_g, ln_b, x);
    }
    k_final<<<48 * 32 / 6, 256, 0, stream>>>(x, Wm, bm, (float*)d_out);
}